// Round 14
// baseline (53.566 us; speedup 1.0000x reference)
//
#include <hip/hip_runtime.h>

// EKF_v2: B=16384, N=128, DX=5, DZ=2.
// R13 (self-contained, PASSED 43.4us, VGPR 68) + ONE change: all 4
// B-fragments prebuilt before the MFMA loop so the 24-VGPR pw1/pb1 tables
// die early (net -8 VGPR, target <=64 -> 8 waves/SIMD, occupancy 2x).
// R12's replay-only failure is attributed to the now-removed d_ws channel
// (first call was bit-correct; regalloc is deterministic).

#define NBPB 4  // batches (=waves) per block

typedef __bf16 bf16x8 __attribute__((ext_vector_type(8)));
typedef float  f32x16 __attribute__((ext_vector_type(16)));

__global__ __launch_bounds__(256) void ekf_fused(
    const float* __restrict__ state_old,  // (B,128,5)
    const float* __restrict__ y_obs,      // (B,128,2)
    const float* __restrict__ encoding,   // (B,128)
    const float* __restrict__ pw1,        // (2,16)
    const float* __restrict__ pb1,        // (16)
    const float* __restrict__ pw2,        // (16,32)
    const float* __restrict__ pb2,        // (32)
    const float* __restrict__ pw3,        // (32,2)
    const float* __restrict__ pb3,        // (2)
    const float* __restrict__ nw1,        // (128,32)
    const float* __restrict__ nb1,        // (32)
    const float* __restrict__ nw2,        // (32,2)
    const float* __restrict__ nb2,        // (2)
    const float* __restrict__ lob,        // (2)
    const float* __restrict__ fob,        // (2)
    float* __restrict__ out)              // (B,128,5)
{
    __shared__ __align__(16) float s_state[NBPB * 640];

    const int t = threadIdx.x;
    const int base = blockIdx.x * NBPB;

    // ---- stage state (coalesced float4) ----
    {
        const float4* src = (const float4*)(state_old + (size_t)base * 640);
        float4* dst = (float4*)s_state;
        #pragma unroll
        for (int i = t; i < NBPB * 160; i += 256) dst[i] = src[i];
    }
    __syncthreads();

    const int w = t >> 6;    // wave = batch within block
    const int l = t & 63;
    const int c = l & 31;    // column / particle-in-group
    const int h = l >> 5;    // lane half -> k-slice & ownership
    const size_t b = (size_t)base + w;

    // ---- noise MLP: j = c, k-range split across halves ----
    float diag0, diag1;
    {
        const float4* eg4 = (const float4*)(encoding + b * 128) + h * 16;
        const float* wp = nw1 + (size_t)(h * 64) * 32 + c; // k = h*64 + 4*kk + r
        float a0 = 0.f, a1 = 0.f, a2 = 0.f, a3 = 0.f;
        #pragma unroll
        for (int kk = 0; kk < 16; ++kk) {
            float4 e4 = eg4[kk];
            a0 = fmaf(e4.x, wp[(4 * kk + 0) * 32], a0);
            a1 = fmaf(e4.y, wp[(4 * kk + 1) * 32], a1);
            a2 = fmaf(e4.z, wp[(4 * kk + 2) * 32], a2);
            a3 = fmaf(e4.w, wp[(4 * kk + 3) * 32], a3);
        }
        float acc = (a0 + a1) + (a2 + a3);
        acc += __shfl_xor(acc, 32, 64);   // combine k-halves
        acc += nb1[c];
        float hh = fmaxf(acc, 0.f);
        float d0 = hh * nw2[2 * c + 0];
        float d1 = hh * nw2[2 * c + 1];
        #pragma unroll
        for (int off = 1; off < 32; off <<= 1) {
            d0 += __shfl_xor(d0, off, 64);
            d1 += __shfl_xor(d1, off, 64);
        }
        float e0 = d0 + nb2[0] + lob[0];
        float e1 = d1 + nb2[1] + lob[1];
        diag0 = fmaf(e0, e0, fob[0]);
        diag1 = fmaf(e1, e1, fob[1]);
    }

    const float* sp = s_state + w * 640;

    // ---- prebuild all 4 B-fragments (pw1/pb1 tables die after this) ----
    bf16x8 bfr[4];
    {
        const float4 pw1a0 = *(const float4*)(pw1 + 8 * h);
        const float4 pw1a1 = *(const float4*)(pw1 + 8 * h + 4);
        const float4 pw1b0 = *(const float4*)(pw1 + 16 + 8 * h);
        const float4 pw1b1 = *(const float4*)(pw1 + 16 + 8 * h + 4);
        const float4 pb1k0 = *(const float4*)(pb1 + 8 * h);
        const float4 pb1k1 = *(const float4*)(pb1 + 8 * h + 4);
        #pragma unroll
        for (int m = 0; m < 4; ++m) {
            const float* s5 = sp + (c + 32 * m) * 5;
            float v = s5[3], td = s5[4];
            bf16x8 bf;
            bf[0] = (__bf16)fmaxf(0.f, fmaf(v, pw1a0.x, fmaf(td, pw1b0.x, pb1k0.x)));
            bf[1] = (__bf16)fmaxf(0.f, fmaf(v, pw1a0.y, fmaf(td, pw1b0.y, pb1k0.y)));
            bf[2] = (__bf16)fmaxf(0.f, fmaf(v, pw1a0.z, fmaf(td, pw1b0.z, pb1k0.z)));
            bf[3] = (__bf16)fmaxf(0.f, fmaf(v, pw1a0.w, fmaf(td, pw1b0.w, pb1k0.w)));
            bf[4] = (__bf16)fmaxf(0.f, fmaf(v, pw1a1.x, fmaf(td, pw1b1.x, pb1k1.x)));
            bf[5] = (__bf16)fmaxf(0.f, fmaf(v, pw1a1.y, fmaf(td, pw1b1.y, pb1k1.y)));
            bf[6] = (__bf16)fmaxf(0.f, fmaf(v, pw1a1.z, fmaf(td, pw1b1.z, pb1k1.z)));
            bf[7] = (__bf16)fmaxf(0.f, fmaf(v, pw1a1.w, fmaf(td, pw1b1.w, pb1k1.w)));
            bfr[m] = bf;
        }
    }

    // ---- epilogue tables in registers (as R13) ----
    float4 pb2v[4], pw3lo[4], pw3hi[4];
    #pragma unroll
    for (int gr = 0; gr < 4; ++gr) {
        pb2v[gr]  = *(const float4*)(pb2 + 8 * gr + 4 * h);
        pw3lo[gr] = *(const float4*)(pw3 + 16 * gr + 8 * h);
        pw3hi[gr] = *(const float4*)(pw3 + 16 * gr + 8 * h + 4);
    }
    // A-fragment from pw2 directly: afr[q] = bf16(pw2[(8h+q)*32 + c])
    bf16x8 afrag;
    #pragma unroll
    for (int q = 0; q < 8; ++q)
        afrag[q] = (__bf16)pw2[(8 * h + q) * 32 + c];
    f32x16 cinit;
    #pragma unroll
    for (int gr = 0; gr < 4; ++gr) {
        cinit[4 * gr + 0] = pb2v[gr].x;
        cinit[4 * gr + 1] = pb2v[gr].y;
        cinit[4 * gr + 2] = pb2v[gr].z;
        cinit[4 * gr + 3] = pb2v[gr].w;
    }

    // ---- MFMA per m: D = pw2^T @ h1 + pb2; epilogue 32->2 on VALU ----
    float o3m[4], o4m[4];
    #pragma unroll
    for (int m = 0; m < 4; ++m) {
        f32x16 acc = __builtin_amdgcn_mfma_f32_32x32x16_bf16(afrag, bfr[m], cinit, 0, 0, 0);
        float o3 = 0.f, o4 = 0.f;
        #pragma unroll
        for (int gr = 0; gr < 4; ++gr) {
            float r0 = fmaxf(acc[4 * gr + 0], 0.f);
            float r1 = fmaxf(acc[4 * gr + 1], 0.f);
            float r2 = fmaxf(acc[4 * gr + 2], 0.f);
            float r3 = fmaxf(acc[4 * gr + 3], 0.f);
            o3 = fmaf(r0, pw3lo[gr].x, o3); o4 = fmaf(r0, pw3lo[gr].y, o4);
            o3 = fmaf(r1, pw3lo[gr].z, o3); o4 = fmaf(r1, pw3lo[gr].w, o4);
            o3 = fmaf(r2, pw3hi[gr].x, o3); o4 = fmaf(r2, pw3hi[gr].y, o4);
            o3 = fmaf(r3, pw3hi[gr].z, o3); o4 = fmaf(r3, pw3hi[gr].w, o4);
        }
        o3m[m] = o3; o4m[m] = o4;
    }
    #pragma unroll
    for (int m = 0; m < 4; ++m) {
        o3m[m] += __shfl_xor(o3m[m], 32, 64);  // combine h2-row halves
        o4m[m] += __shfl_xor(o4m[m], 32, 64);
    }

    // ---- owned particles (half h owns m = 2h, 2h+1) ----
    const float pb30 = pb3[0], pb31 = pb3[1];
    float o3s0 = h ? o3m[2] : o3m[0];
    float o3s1 = h ? o3m[3] : o3m[1];
    float o4s0 = h ? o4m[2] : o4m[0];
    float o4s1 = h ? o4m[3] : o4m[1];
    float xpo[2][5];
    #pragma unroll
    for (int mm = 0; mm < 2; ++mm) {
        const float* s5 = sp + (c + 32 * (2 * h + mm)) * 5;
        float s0 = s5[0], s1 = s5[1], s2 = s5[2], v = s5[3], td = s5[4];
        float th = s2 + td;
        xpo[mm][0] = fmaf(v, __sinf(th), s0);
        xpo[mm][1] = fmaf(v, __cosf(th), s1);
        xpo[mm][2] = th;
        xpo[mm][3] = v  + (mm ? o3s1 : o3s0) + pb30;
        xpo[mm][4] = td + (mm ? o4s1 : o4s0) + pb31;
    }

    // ---- raw moments: ONE butterfly phase (6 levels), 14 chains ----
    float red[14];
    #pragma unroll
    for (int i = 0; i < 5; ++i) red[i] = xpo[0][i] + xpo[1][i];
    red[5]  = xpo[0][0] * xpo[0][3] + xpo[1][0] * xpo[1][3];
    red[6]  = xpo[0][0] * xpo[0][4] + xpo[1][0] * xpo[1][4];
    red[7]  = xpo[0][1] * xpo[0][3] + xpo[1][1] * xpo[1][3];
    red[8]  = xpo[0][1] * xpo[0][4] + xpo[1][1] * xpo[1][4];
    red[9]  = xpo[0][2] * xpo[0][3] + xpo[1][2] * xpo[1][3];
    red[10] = xpo[0][2] * xpo[0][4] + xpo[1][2] * xpo[1][4];
    red[11] = xpo[0][3] * xpo[0][3] + xpo[1][3] * xpo[1][3];
    red[12] = xpo[0][3] * xpo[0][4] + xpo[1][3] * xpo[1][4];
    red[13] = xpo[0][4] * xpo[0][4] + xpo[1][4] * xpo[1][4];
    #pragma unroll
    for (int off = 1; off < 64; off <<= 1) {
        #pragma unroll
        for (int r = 0; r < 14; ++r)
            red[r] += __shfl_xor(red[r], off, 64);
    }

    // ---- covariances + analytic 2x2 solve ----
    const float inv  = 1.0f / 127.0f;
    const float minv = inv * 0.0078125f; // 1/(127*128)
    float S00 = red[5]  * inv - red[0] * red[3] * minv;
    float S01 = red[6]  * inv - red[0] * red[4] * minv;
    float S10 = red[7]  * inv - red[1] * red[3] * minv;
    float S11 = red[8]  * inv - red[1] * red[4] * minv;
    float S20 = red[9]  * inv - red[2] * red[3] * minv;
    float S21 = red[10] * inv - red[2] * red[4] * minv;
    float S30 = red[11] * inv - red[3] * red[3] * minv;
    float S31 = red[12] * inv - red[3] * red[4] * minv;
    float S40 = S31;
    float S41 = red[13] * inv - red[4] * red[4] * minv;
    float p00 = S30 + diag0, p01 = S31, p10 = S40, p11 = S41 + diag1;
    float rdet = 1.0f / (p00 * p11 - p01 * p10);
    float Ka0 = (p11 * S00 - p01 * S01) * rdet, Kb0 = (p00 * S01 - p10 * S00) * rdet;
    float Ka1 = (p11 * S10 - p01 * S11) * rdet, Kb1 = (p00 * S11 - p10 * S10) * rdet;
    float Ka2 = (p11 * S20 - p01 * S21) * rdet, Kb2 = (p00 * S21 - p10 * S20) * rdet;
    float Ka3 = (p11 * S30 - p01 * S31) * rdet, Kb3 = (p00 * S31 - p10 * S30) * rdet;
    float Ka4 = (p11 * S40 - p01 * S41) * rdet, Kb4 = (p00 * S41 - p10 * S40) * rdet;

    // ---- Kalman update + direct stores (2 owned particles) ----
    #pragma unroll
    for (int mm = 0; mm < 2; ++mm) {
        const int p = c + 32 * (2 * h + mm);
        const float2 yy = *(const float2*)(y_obs + (b * 128 + (size_t)p) * 2);
        float i0 = yy.x - xpo[mm][3];
        float i1 = yy.y - xpo[mm][4];
        float* o = out + (b * 128 + (size_t)p) * 5;
        o[0] = xpo[mm][0] + i0 * Ka0 + i1 * Kb0;
        o[1] = xpo[mm][1] + i0 * Ka1 + i1 * Kb1;
        o[2] = xpo[mm][2] + i0 * Ka2 + i1 * Kb2;
        o[3] = xpo[mm][3] + i0 * Ka3 + i1 * Kb3;
        o[4] = xpo[mm][4] + i0 * Ka4 + i1 * Kb4;
    }
}

extern "C" void kernel_launch(void* const* d_in, const int* in_sizes, int n_in,
                              void* d_out, int out_size, void* d_ws, size_t ws_size,
                              hipStream_t stream) {
    const float* state_old = (const float*)d_in[0];
    const float* y_obs     = (const float*)d_in[1];
    const float* encoding  = (const float*)d_in[2];
    const float* pw1 = (const float*)d_in[3];
    const float* pb1 = (const float*)d_in[4];
    const float* pw2 = (const float*)d_in[5];
    const float* pb2 = (const float*)d_in[6];
    const float* pw3 = (const float*)d_in[7];
    const float* pb3 = (const float*)d_in[8];
    const float* nw1 = (const float*)d_in[9];
    const float* nb1 = (const float*)d_in[10];
    const float* nw2 = (const float*)d_in[11];
    const float* nb2 = (const float*)d_in[12];
    const float* lob = (const float*)d_in[13];
    const float* fob = (const float*)d_in[14];
    float* out = (float*)d_out;

    const int B = 16384;
    dim3 grid(B / NBPB);
    dim3 block(256);
    hipLaunchKernelGGL(ekf_fused, grid, block, 0, stream,
                       state_old, y_obs, encoding,
                       pw1, pb1, pw2, pb2, pw3, pb3,
                       nw1, nb1, nw2, nb2, lob, fob, out);
}